// Round 9
// baseline (1285.494 us; speedup 1.0000x reference)
//
#include <hip/hip_runtime.h>
#include <hip/hip_bf16.h>
#include <stdint.h>

typedef short short8 __attribute__((ext_vector_type(8)));
typedef float floatx4 __attribute__((ext_vector_type(4)));

static constexpr int KTOT = 4096;
static constexpr int NTOT = 16384;
static constexpr int MTOT = 8192;

#define GLOAD_LDS16(g, l)                                              \
  __builtin_amdgcn_global_load_lds(                                    \
      (const __attribute__((address_space(1))) void*)(g),              \
      (__attribute__((address_space(3))) void*)(l), 16, 0, 0)

__device__ __forceinline__ uint32_t pack2_bf16_rne(float lo, float hi) {
  uint32_t a = __builtin_bit_cast(uint32_t, lo);
  uint32_t b = __builtin_bit_cast(uint32_t, hi);
  a += 0x7FFFu + ((a >> 16) & 1u);
  b += 0x7FFFu + ((b >> 16) & 1u);
  return __builtin_amdgcn_perm(b, a, 0x07060302u);  // hi16(b)<<16 | hi16(a)
}

// ---------------- converters ----------------

__global__ __launch_bounds__(256) void cvt_x_kernel(
    const float* __restrict__ X, ushort* __restrict__ Xb) {
  const size_t i = (size_t)blockIdx.x * 256 + threadIdx.x;  // 8 floats/thread
  const float4 a = *reinterpret_cast<const float4*>(X + i * 8);
  const float4 b = *reinterpret_cast<const float4*>(X + i * 8 + 4);
  uint4 o;
  o.x = pack2_bf16_rne(a.x, a.y);
  o.y = pack2_bf16_rne(a.z, a.w);
  o.z = pack2_bf16_rne(b.x, b.y);
  o.w = pack2_bf16_rne(b.z, b.w);
  *reinterpret_cast<uint4*>(Xb + i * 8) = o;
}

__global__ __launch_bounds__(256) void cvt_w_kernel(
    const uint32_t* __restrict__ Wp, ushort* __restrict__ Wb) {
  const size_t i = (size_t)blockIdx.x * 256 + threadIdx.x;  // 4 words -> 8 bf16
  const uint4 w = *reinterpret_cast<const uint4*>(Wp + i * 4);
  const uint32_t wd[4] = {w.x, w.y, w.z, w.w};
  uint4 o;
  uint32_t* op = reinterpret_cast<uint32_t*>(&o);
  #pragma unroll
  for (int p = 0; p < 4; ++p) {
    // each int32 word holds one packed byte: low nibble = value 2q, high = 2q+1
    int v0 = ((int)(wd[p] << 28)) >> 28;
    int v1 = ((int)(wd[p] << 24)) >> 28;
    uint32_t f0 = __builtin_bit_cast(uint32_t, (float)v0);  // exact in bf16
    uint32_t f1 = __builtin_bit_cast(uint32_t, (float)v1);
    op[p] = __builtin_amdgcn_perm(f1, f0, 0x07060302u);
  }
  *reinterpret_cast<uint4*>(Wb + i * 8) = o;
}

// ------- 256x256 bf16 GEMM: m201-style 4-phase/K-tile (BK=64), 2-deep dbuf -------
// 512 threads = 8 waves (2 M x 4 N). Per-wave output 128x64 -> acc[8][4].
// LDS: [buf][half][2 j-spans][64 rows][64 cols] x {A,B} = 128 KB. Row = 8 chunks
// of 16 B; swizzle c_phys = c_log ^ (row&7) (involution; staging source
// pre-swizzled per-lane, LDS dest linear; read applies the same XOR).
// Staging: thread t -> LDS ushort t*8 (row t>>3, chunk t&7); gload wave base
// MUST be wv*512 ushorts (64 lanes x 16 B). [round-8 bug: wv*1024 -> NaN]
// All barriers are single asm blocks with "memory" clobber so no LDS op can
// slip between a waitcnt and its s_barrier (rounds 5-7 invariant).

static constexpr int BM = 256, BN = 256, BK = 64;
static constexpr int NT = KTOT / BK;  // 64 K-tiles

#define BAR_MEM()  asm volatile("s_barrier" ::: "memory")
#define LGKM0()                                                        \
  { asm volatile("s_waitcnt lgkmcnt(0)" ::: "memory");                 \
    __builtin_amdgcn_sched_barrier(0); }

#define MFMA_Q(MB, NB)                                                 \
  __builtin_amdgcn_s_setprio(1);                                       \
  _Pragma("unroll")                                                    \
  for (int m = 0; m < 4; ++m) {                                        \
    _Pragma("unroll")                                                  \
    for (int n = 0; n < 2; ++n) {                                      \
      acc[(MB)+m][(NB)+n] = __builtin_amdgcn_mfma_f32_16x16x32_bf16(   \
          aK0[m], bK0[n], acc[(MB)+m][(NB)+n], 0, 0, 0);               \
      acc[(MB)+m][(NB)+n] = __builtin_amdgcn_mfma_f32_16x16x32_bf16(   \
          aK1[m], bK1[n], acc[(MB)+m][(NB)+n], 0, 0, 0);               \
    }                                                                  \
  }                                                                    \
  __builtin_amdgcn_s_setprio(0);

__global__ __launch_bounds__(512, 2) void gemm_bf16_256_kernel(
    const ushort* __restrict__ Xb,   // [MTOT][KTOT] bf16
    const ushort* __restrict__ Wb,   // [NTOT][KTOT] bf16 (B^T layout)
    const float* __restrict__ scale,
    const float* __restrict__ bias,
    float* __restrict__ Y)
{
  __shared__ ushort As[2 * 16384];   // buf*16384 + half*8192 + j*4096 + row*64 + chunk*8
  __shared__ ushort Bs[2 * 16384];

  const int t    = threadIdx.x;
  const int lane = t & 63;
  const int wv   = t >> 6;       // 0..7
  const int wr   = wv >> 2;      // 0..1  (M half)
  const int wcn  = wv & 3;       // 0..3  (N quarter)

  // XCD mapping: xcd owns 4 M-tile rows; s>>2 sweeps N so all XCDs share W panels via L3
  const int wg  = blockIdx.x;          // 2048 blocks = 32 bm x 64 bn
  const int xcd = wg & 7;
  const int s   = wg >> 3;             // 0..255
  const int bm0 = (xcd * 4 + (s & 3)) * BM;
  const int bn0 = (s >> 2) * BN;

  // ---- staging addressing: thread t covers row t>>3 of a 64-row span, phys
  // chunk t&7; source column pre-swizzled by the involution.
  const int trow = t >> 3;                               // 0..63
  const int scol = 8 * ((t & 7) ^ (trow & 7));
  const ushort* agA = Xb + (size_t)(bm0 + trow) * KTOT + scol;
  const ushort* agB = Wb + (size_t)(bn0 + trow) * KTOT + scol;
  const int ldst = wv * 512;   // wave-uniform LDS dest base (+lane*16B by HW)  [FIXED]

  // ---- ds_read fragment addressing: row&7 == lane&7 for all frag rows
  const int p   = lane >> 4;
  const int l7  = lane & 7;
  const int l15 = lane & 15;
  const int co0 = 8 * (p ^ l7);          // kk=0 chunk offset
  const int co1 = 8 * ((4 | p) ^ l7);    // kk=1
  const int abase = wr * 8192 + l15 * 64;
  const int bbase = (wcn >> 1) * 8192 + (wcn & 1) * 4096 + l15 * 64;

  floatx4 acc[8][4];
  #pragma unroll
  for (int m = 0; m < 8; ++m)
    #pragma unroll
    for (int n = 0; n < 4; ++n)
      acc[m][n] = (floatx4){0.f, 0.f, 0.f, 0.f};

  // ---- prologue: stage tile 0 into buf 0 (8 half-tile loads), publish
  #pragma unroll
  for (int h = 0; h < 2; ++h)
    #pragma unroll
    for (int j = 0; j < 2; ++j) {
      GLOAD_LDS16(agA + (size_t)(h * 128 + j * 64) * KTOT, As + h * 8192 + j * 4096 + ldst);
      GLOAD_LDS16(agB + (size_t)(h * 128 + j * 64) * KTOT, Bs + h * 8192 + j * 4096 + ldst);
    }
  asm volatile("s_waitcnt vmcnt(0)\ns_barrier" ::: "memory");

  short8 aK0[4], aK1[4], bK0[2], bK1[2];

  for (int kt = 0; kt < NT; ++kt) {
    const int bufo = (kt & 1) << 14;
    const int sbo  = ((kt + 1) & 1) << 14;
    const size_t koff = (size_t)(kt + 1) * BK;
    const bool st = (kt + 1) < NT;
    const ushort* Abuf = As + bufo;
    const ushort* Bbuf = Bs + bufo;

    // ======== phase 0: read A m0-3 + B n0-1; stage A-h0; MFMA Q(0,0) ========
    #pragma unroll
    for (int m = 0; m < 4; ++m) {
      aK0[m] = *reinterpret_cast<const short8*>(Abuf + abase + m * 1024 + co0);
      aK1[m] = *reinterpret_cast<const short8*>(Abuf + abase + m * 1024 + co1);
    }
    #pragma unroll
    for (int n = 0; n < 2; ++n) {
      bK0[n] = *reinterpret_cast<const short8*>(Bbuf + bbase + n * 1024 + co0);
      bK1[n] = *reinterpret_cast<const short8*>(Bbuf + bbase + n * 1024 + co1);
    }
    if (st) {
      GLOAD_LDS16(agA + koff,                        As + sbo + ldst);
      GLOAD_LDS16(agA + koff + (size_t)64 * KTOT,    As + sbo + 4096 + ldst);
    }
    BAR_MEM(); LGKM0();
    MFMA_Q(0, 0);
    BAR_MEM();

    // ======== phase 1: read A m4-7; stage A-h1; MFMA Q(4,0) ========
    #pragma unroll
    for (int m = 0; m < 4; ++m) {
      aK0[m] = *reinterpret_cast<const short8*>(Abuf + abase + (m + 4) * 1024 + co0);
      aK1[m] = *reinterpret_cast<const short8*>(Abuf + abase + (m + 4) * 1024 + co1);
    }
    if (st) {
      GLOAD_LDS16(agA + koff + (size_t)128 * KTOT,   As + sbo + 8192 + ldst);
      GLOAD_LDS16(agA + koff + (size_t)192 * KTOT,   As + sbo + 8192 + 4096 + ldst);
    }
    BAR_MEM(); LGKM0();
    MFMA_Q(4, 0);
    BAR_MEM();

    // ======== phase 2: read B n2-3; stage B-h0 + B-h1; MFMA Q(4,2) ========
    #pragma unroll
    for (int n = 0; n < 2; ++n) {
      bK0[n] = *reinterpret_cast<const short8*>(Bbuf + bbase + (n + 2) * 1024 + co0);
      bK1[n] = *reinterpret_cast<const short8*>(Bbuf + bbase + (n + 2) * 1024 + co1);
    }
    if (st) {
      GLOAD_LDS16(agB + koff,                        Bs + sbo + ldst);
      GLOAD_LDS16(agB + koff + (size_t)64 * KTOT,    Bs + sbo + 4096 + ldst);
      GLOAD_LDS16(agB + koff + (size_t)128 * KTOT,   Bs + sbo + 8192 + ldst);
      GLOAD_LDS16(agB + koff + (size_t)192 * KTOT,   Bs + sbo + 8192 + 4096 + ldst);
    }
    BAR_MEM(); LGKM0();
    MFMA_Q(4, 2);
    BAR_MEM();

    // ======== phase 3: re-read A m0-3; no stage; MFMA Q(0,2); boundary ========
    #pragma unroll
    for (int m = 0; m < 4; ++m) {
      aK0[m] = *reinterpret_cast<const short8*>(Abuf + abase + m * 1024 + co0);
      aK1[m] = *reinterpret_cast<const short8*>(Abuf + abase + m * 1024 + co1);
    }
    BAR_MEM(); LGKM0();
    MFMA_Q(0, 2);
    // boundary: drain stage loads (oldest issued 3 phases ago — cheap) + publish.
    // Single asm: no LDS op can slip between waitcnt and barrier.
    if (st) { asm volatile("s_waitcnt vmcnt(0)\ns_barrier" ::: "memory"); }
    else    { BAR_MEM(); }
  }

  // ---- epilogue: y = acc * scale[col] + bias[col]
  const int crow = (lane >> 4) * 4;  // C/D: row=(lane>>4)*4+reg, col=lane&15 (m89)
  const int ccol = lane & 15;
  #pragma unroll
  for (int n = 0; n < 4; ++n) {
    const int col  = bn0 + wcn * 64 + n * 16 + ccol;
    const float sc = scale[col];
    const float bz = bias[col];
    #pragma unroll
    for (int m = 0; m < 8; ++m) {
      const int row0 = bm0 + wr * 128 + m * 16 + crow;
      float* yp = Y + (size_t)row0 * NTOT + col;
      #pragma unroll
      for (int r = 0; r < 4; ++r)
        yp[(size_t)r * NTOT] = acc[m][n][r] * sc + bz;
    }
  }
}

// ---------------- fallback: fused kernel (round-2 passing version) ----------------

static constexpr int FBM = 128, FBN = 128, FBK = 64;
static constexpr int LDSS = 72;
static constexpr int FNSTEP = KTOT / FBK;

__global__ __launch_bounds__(256) void int4_linear_fused_kernel(
    const float* __restrict__ X,
    const uint32_t* __restrict__ Wp,
    const float* __restrict__ scale,
    const float* __restrict__ bias,
    float* __restrict__ Y)
{
  __shared__ ushort As[FBM * LDSS];
  __shared__ ushort Bs[FBN * LDSS];

  const int t    = threadIdx.x;
  const int lane = t & 63;
  const int wv   = t >> 6;
  const int wr   = wv >> 1;
  const int wc   = wv & 1;
  const int bm0 = blockIdx.y * FBM;
  const int bn0 = blockIdx.x * FBN;
  const int srow = t >> 1;
  const int sh   = t & 1;

  const float*    ag = X  + (size_t)(bm0 + srow) * KTOT + sh * 32;
  const uint32_t* bg = Wp + (size_t)(bn0 + srow) * (KTOT / 2) + sh * 16;

  float4 areg[8];
  uint4  breg[4];
  #pragma unroll
  for (int j = 0; j < 8; ++j) areg[j] = *reinterpret_cast<const float4*>(ag + j * 4);
  #pragma unroll
  for (int j = 0; j < 4; ++j) breg[j] = *reinterpret_cast<const uint4*>(bg + j * 4);

  floatx4 acc[4][4];
  #pragma unroll
  for (int m = 0; m < 4; ++m)
    #pragma unroll
    for (int n = 0; n < 4; ++n)
      acc[m][n] = (floatx4){0.f, 0.f, 0.f, 0.f};

  ushort* adst = &As[srow * LDSS + sh * 32];
  ushort* bdst = &Bs[srow * LDSS + sh * 32];

  for (int ks = 0; ks < FNSTEP; ++ks) {
    {
      uint32_t ab[16];
      #pragma unroll
      for (int j = 0; j < 8; ++j) {
        uint32_t u0 = __builtin_bit_cast(uint32_t, areg[j].x) + 0x8000u;
        uint32_t u1 = __builtin_bit_cast(uint32_t, areg[j].y) + 0x8000u;
        uint32_t u2 = __builtin_bit_cast(uint32_t, areg[j].z) + 0x8000u;
        uint32_t u3 = __builtin_bit_cast(uint32_t, areg[j].w) + 0x8000u;
        ab[2*j]   = __builtin_amdgcn_perm(u1, u0, 0x07060302u);
        ab[2*j+1] = __builtin_amdgcn_perm(u3, u2, 0x07060302u);
      }
      uint32_t bb[16];
      #pragma unroll
      for (int j = 0; j < 4; ++j) {
        const uint32_t wq[4] = {breg[j].x, breg[j].y, breg[j].z, breg[j].w};
        #pragma unroll
        for (int p2 = 0; p2 < 4; ++p2) {
          const uint32_t w = wq[p2];
          int v0 = ((int)(w << 28)) >> 28;
          int v1 = ((int)(w << 24)) >> 28;
          uint32_t f0 = __builtin_bit_cast(uint32_t, (float)v0);
          uint32_t f1 = __builtin_bit_cast(uint32_t, (float)v1);
          bb[j*4 + p2] = __builtin_amdgcn_perm(f1, f0, 0x07060302u);
        }
      }
      #pragma unroll
      for (int j = 0; j < 4; ++j) {
        *reinterpret_cast<uint4*>(adst + j * 8) = *reinterpret_cast<const uint4*>(&ab[j*4]);
        *reinterpret_cast<uint4*>(bdst + j * 8) = *reinterpret_cast<const uint4*>(&bb[j*4]);
      }
    }
    __syncthreads();

    if (ks + 1 < FNSTEP) {
      const float*    ap = ag + (ks + 1) * FBK;
      const uint32_t* bp = bg + (ks + 1) * (FBK / 2);
      #pragma unroll
      for (int j = 0; j < 8; ++j) areg[j] = *reinterpret_cast<const float4*>(ap + j * 4);
      #pragma unroll
      for (int j = 0; j < 4; ++j) breg[j] = *reinterpret_cast<const uint4*>(bp + j * 4);
    }

    #pragma unroll
    for (int kk = 0; kk < 2; ++kk) {
      const int ko = kk * 32 + (lane >> 4) * 8;
      short8 af[4], bf[4];
      #pragma unroll
      for (int m = 0; m < 4; ++m)
        af[m] = *reinterpret_cast<const short8*>(&As[(wr*64 + m*16 + (lane & 15)) * LDSS + ko]);
      #pragma unroll
      for (int n = 0; n < 4; ++n)
        bf[n] = *reinterpret_cast<const short8*>(&Bs[(wc*64 + n*16 + (lane & 15)) * LDSS + ko]);
      #pragma unroll
      for (int m = 0; m < 4; ++m)
        #pragma unroll
        for (int n = 0; n < 4; ++n)
          acc[m][n] = __builtin_amdgcn_mfma_f32_16x16x32_bf16(af[m], bf[n], acc[m][n], 0, 0, 0);
    }
    __syncthreads();
  }

  const int crow = (lane >> 4) * 4;
  const int ccol = lane & 15;
  #pragma unroll
  for (int n = 0; n < 4; ++n) {
    const int col  = bn0 + wc * 64 + n * 16 + ccol;
    const float sv = scale[col];
    const float bz = bias[col];
    #pragma unroll
    for (int m = 0; m < 4; ++m) {
      const int row0 = bm0 + wr * 64 + m * 16 + crow;
      float* yp = Y + (size_t)row0 * NTOT + col;
      #pragma unroll
      for (int r = 0; r < 4; ++r)
        yp[(size_t)r * NTOT] = acc[m][n][r] * sv + bz;
    }
  }
}

// ---------------- launch ----------------

extern "C" void kernel_launch(void* const* d_in, const int* in_sizes, int n_in,
                              void* d_out, int out_size, void* d_ws, size_t ws_size,
                              hipStream_t stream) {
  (void)in_sizes; (void)n_in; (void)out_size;
  const float*    X     = (const float*)d_in[0];
  const uint32_t* Wp    = (const uint32_t*)d_in[1];
  const float*    scale = (const float*)d_in[2];
  const float*    bias  = (const float*)d_in[3];
  float*          Y     = (float*)d_out;

  const size_t xb_bytes = (size_t)MTOT * KTOT * 2;          // 67 MB
  const size_t wb_bytes = (size_t)NTOT * KTOT * 2;          // 134 MB
  if (ws_size >= xb_bytes + wb_bytes) {
    ushort* Xb = (ushort*)d_ws;
    ushort* Wb = (ushort*)((char*)d_ws + xb_bytes);
    cvt_x_kernel<<<(MTOT * KTOT) / (8 * 256), 256, 0, stream>>>(X, Xb);
    cvt_w_kernel<<<(NTOT * KTOT / 2) / (4 * 256), 256, 0, stream>>>(Wp, Wb);
    gemm_bf16_256_kernel<<<(MTOT / BM) * (NTOT / BN), 512, 0, stream>>>(Xb, Wb, scale, bias, Y);
  } else {
    dim3 grid(NTOT / FBN, MTOT / FBM);
    int4_linear_fused_kernel<<<grid, 256, 0, stream>>>(X, Wp, scale, bias, Y);
  }
}

// Round 10
// 1081.917 us; speedup vs baseline: 1.1882x; 1.1882x over previous
//
#include <hip/hip_runtime.h>
#include <hip/hip_bf16.h>
#include <stdint.h>

typedef short short8 __attribute__((ext_vector_type(8)));
typedef float floatx4 __attribute__((ext_vector_type(4)));

static constexpr int KTOT = 4096;
static constexpr int NTOT = 16384;
static constexpr int MTOT = 8192;

#define GLOAD_LDS16(g, l)                                              \
  __builtin_amdgcn_global_load_lds(                                    \
      (const __attribute__((address_space(1))) void*)(g),              \
      (__attribute__((address_space(3))) void*)(l), 16, 0, 0)

__device__ __forceinline__ uint32_t pack2_bf16_rne(float lo, float hi) {
  uint32_t a = __builtin_bit_cast(uint32_t, lo);
  uint32_t b = __builtin_bit_cast(uint32_t, hi);
  a += 0x7FFFu + ((a >> 16) & 1u);
  b += 0x7FFFu + ((b >> 16) & 1u);
  return __builtin_amdgcn_perm(b, a, 0x07060302u);  // hi16(b)<<16 | hi16(a)
}

// ---------------- converters ----------------

__global__ __launch_bounds__(256) void cvt_x_kernel(
    const float* __restrict__ X, ushort* __restrict__ Xb) {
  const size_t i = (size_t)blockIdx.x * 256 + threadIdx.x;  // 8 floats/thread
  const float4 a = *reinterpret_cast<const float4*>(X + i * 8);
  const float4 b = *reinterpret_cast<const float4*>(X + i * 8 + 4);
  uint4 o;
  o.x = pack2_bf16_rne(a.x, a.y);
  o.y = pack2_bf16_rne(a.z, a.w);
  o.z = pack2_bf16_rne(b.x, b.y);
  o.w = pack2_bf16_rne(b.z, b.w);
  *reinterpret_cast<uint4*>(Xb + i * 8) = o;
}

__global__ __launch_bounds__(256) void cvt_w_kernel(
    const uint32_t* __restrict__ Wp, ushort* __restrict__ Wb) {
  const size_t i = (size_t)blockIdx.x * 256 + threadIdx.x;  // 4 words -> 8 bf16
  const uint4 w = *reinterpret_cast<const uint4*>(Wp + i * 4);
  const uint32_t wd[4] = {w.x, w.y, w.z, w.w};
  uint4 o;
  uint32_t* op = reinterpret_cast<uint32_t*>(&o);
  #pragma unroll
  for (int p = 0; p < 4; ++p) {
    // each int32 word holds one packed byte: low nibble = value 2q, high = 2q+1
    int v0 = ((int)(wd[p] << 28)) >> 28;
    int v1 = ((int)(wd[p] << 24)) >> 28;
    uint32_t f0 = __builtin_bit_cast(uint32_t, (float)v0);  // exact in bf16
    uint32_t f1 = __builtin_bit_cast(uint32_t, (float)v1);
    op[p] = __builtin_amdgcn_perm(f1, f0, 0x07060302u);
  }
  *reinterpret_cast<uint4*>(Wb + i * 8) = o;
}

// ------- 256x256 bf16 GEMM: round-7 coarse pipeline x round-9 conflict-free LDS -------
// 512 threads = 8 waves (2 M x 4 N). Per-wave output 128x64 -> acc[8][4].
// LDS: A ring 4 x 16KB + B ring 4 x 16KB = 128 KB (1 block/CU).
// Layout (conflict-free, measured 0 in round 9's BK=64 variant): BK=32 tile stored
// as 128-B LDS rows, TWO M-rows per LDS row: ldsrow = m>>1; logical chunk
// c_log = (m&1)<<2 | kchunk (kchunk = k16B-granule 0..3); physical chunk
// c_phys = c_log ^ (ldsrow&7). Every 16-lane b128 read group hits all 8
// bank-quads exactly 2x = wave64 floor.
// Schedule (round 7, best measured): iter kt issues 12 ds_read_b128 for tile
// kt+1's fragments, stages tile kt+3 (4 global_load_lds), MFMAs tile kt from
// regs read last iteration; single boundary asm{vmcnt(4); s_barrier} per tile
// publishes tile kt+2 (tile kt+3's 4 loads stay in flight). Named frag sets,
// unroll-by-2 (rule #20).

static constexpr int BM = 256, BN = 256, BK = 32;
static constexpr int NT = KTOT / BK;  // 128 K-tiles

#define READ_FRAGS(AF0, AF1, BF, buf)                                   \
  {                                                                     \
    const ushort* Ab_ = As + (buf) * 8192 + abase + laneoff;            \
    const ushort* Bb_ = Bs + (buf) * 8192 + bbase + laneoff;            \
    _Pragma("unroll")                                                   \
    for (int n = 0; n < 4; ++n)                                         \
      BF[n] = *reinterpret_cast<const short8*>(Bb_ + n * 512);          \
    _Pragma("unroll")                                                   \
    for (int m = 0; m < 4; ++m)                                         \
      AF0[m] = *reinterpret_cast<const short8*>(Ab_ + m * 512);         \
    _Pragma("unroll")                                                   \
    for (int m = 0; m < 4; ++m)                                         \
      AF1[m] = *reinterpret_cast<const short8*>(Ab_ + (m + 4) * 512);   \
  }

#define STAGE(st_)                                                      \
  if ((st_) < NT) {                                                     \
    const int sb_ = (st_) & 3;                                          \
    const size_t kof_ = (size_t)(st_) * BK;                             \
    GLOAD_LDS16(agA + kof_,           aldsw + sb_ * 8192);              \
    GLOAD_LDS16(agA + kof_ + rowstep, aldsw + sb_ * 8192 + 4096);       \
    GLOAD_LDS16(agB + kof_,           bldsw + sb_ * 8192);              \
    GLOAD_LDS16(agB + kof_ + rowstep, bldsw + sb_ * 8192 + 4096);       \
  }

#define MFMA_CLUSTER(AF0, AF1, BF)                                      \
  __builtin_amdgcn_s_setprio(1);                                        \
  _Pragma("unroll")                                                     \
  for (int m = 0; m < 4; ++m)                                           \
    _Pragma("unroll")                                                   \
    for (int n = 0; n < 4; ++n)                                         \
      acc[m][n] = __builtin_amdgcn_mfma_f32_16x16x32_bf16(AF0[m], BF[n], acc[m][n], 0, 0, 0); \
  _Pragma("unroll")                                                     \
  for (int m = 0; m < 4; ++m)                                           \
    _Pragma("unroll")                                                   \
    for (int n = 0; n < 4; ++n)                                         \
      acc[m + 4][n] = __builtin_amdgcn_mfma_f32_16x16x32_bf16(AF1[m], BF[n], acc[m + 4][n], 0, 0, 0); \
  __builtin_amdgcn_s_setprio(0);

#define BOUNDARY(k_)                                                    \
  if ((k_) + 3 < NT) { asm volatile("s_waitcnt vmcnt(4)\ns_barrier" ::: "memory"); } \
  else               { asm volatile("s_waitcnt vmcnt(0)\ns_barrier" ::: "memory"); }

__global__ __launch_bounds__(512, 2) void gemm_bf16_256_kernel(
    const ushort* __restrict__ Xb,   // [MTOT][KTOT] bf16
    const ushort* __restrict__ Wb,   // [NTOT][KTOT] bf16 (B^T layout)
    const float* __restrict__ scale,
    const float* __restrict__ bias,
    float* __restrict__ Y)
{
  __shared__ ushort As[4 * 8192];   // buf*8192 + ldsrow*64 + c_phys*8
  __shared__ ushort Bs[4 * 8192];

  const int t    = threadIdx.x;
  const int lane = t & 63;
  const int wv   = t >> 6;       // 0..7
  const int wr   = wv >> 2;      // 0..1  (M half)
  const int wcn  = wv & 3;       // 0..3  (N quarter)

  // XCD mapping: xcd owns 4 M-tile rows; s>>2 sweeps N so all XCDs share W panels via L3
  const int wg  = blockIdx.x;          // 2048 blocks = 32 bm x 64 bn
  const int xcd = wg & 7;
  const int s   = wg >> 3;             // 0..255
  const int bm0 = (xcd * 4 + (s & 3)) * BM;
  const int bn0 = (s >> 2) * BN;

  // ---- staging addressing (pre-swizzled global source, linear LDS dest)
  // thread t writes LDS (ldsrow = t>>3, c_phys = t&7) of a 64-ldsrow span.
  // stored content must be logical c_log = (t&7) ^ ((t>>3)&7):
  //   m_loc = 2*(t>>3) + (c_log>>2)  (0..127), kchunk = c_log & 3
  const int clg  = (t & 7) ^ ((t >> 3) & 7);
  const int srow = ((t >> 3) << 1) | (clg >> 2);
  const int scol = (clg & 3) * 8;
  const ushort* agA = Xb + (size_t)(bm0 + srow) * KTOT + scol;
  const ushort* agB = Wb + (size_t)(bn0 + srow) * KTOT + scol;
  const size_t rowstep = (size_t)128 * KTOT;   // second 64-ldsrow span (+128 M-rows)
  ushort* aldsw = As + wv * 512;               // wave-uniform base (+lane*16B by HW)
  ushort* bldsw = Bs + wv * 512;

  // ---- ds_read fragment addressing: row = (frag base) + l15, kchunk = p
  //   ldsrow = rowbase/2 + (l15>>1); c_log = (l15&1)<<2 | p;
  //   c_phys = c_log ^ ((l15>>1)&7)   (rowbase/2 multiples of 8 vanish mod 8)
  const int p    = lane >> 4;
  const int l15  = lane & 15;
  const int cph  = (((l15 & 1) << 2) | p) ^ ((l15 >> 1) & 7);
  const int laneoff = (l15 >> 1) * 64 + cph * 8;
  const int abase = wr * 4096;    // wr*64 ldsrows * 64 ushorts
  const int bbase = wcn * 2048;   // wcn*32 ldsrows
  // per-m / per-n step: 8 ldsrows = 512 ushorts

  floatx4 acc[8][4];
  #pragma unroll
  for (int m = 0; m < 8; ++m)
    #pragma unroll
    for (int n = 0; n < 4; ++n)
      acc[m][n] = (floatx4){0.f, 0.f, 0.f, 0.f};

  // ---- prologue: stage tiles 0,1,2 (12 loads); publish tiles 0,1 (vmcnt(4))
  #pragma unroll
  for (int pt = 0; pt < 3; ++pt) {
    const size_t kof = (size_t)pt * BK;
    GLOAD_LDS16(agA + kof,           aldsw + pt * 8192);
    GLOAD_LDS16(agA + kof + rowstep, aldsw + pt * 8192 + 4096);
    GLOAD_LDS16(agB + kof,           bldsw + pt * 8192);
    GLOAD_LDS16(agB + kof + rowstep, bldsw + pt * 8192 + 4096);
  }
  asm volatile("s_waitcnt vmcnt(4)\ns_barrier" ::: "memory");

  // fragment sets (named; no runtime-indexed reg arrays)
  short8 a0A[4], a1A[4], bA[4];
  short8 a0B[4], a1B[4], bB[4];
  READ_FRAGS(a0A, a1A, bA, 0);   // tile 0 fragments

  for (int kt = 0; kt < NT; kt += 2) {
    // ---- even sub-iter: read tile kt+1 frags; stage kt+3; MFMA tile kt
    READ_FRAGS(a0B, a1B, bB, (kt + 1) & 3);
    STAGE(kt + 3);
    MFMA_CLUSTER(a0A, a1A, bA);
    BOUNDARY(kt);

    // ---- odd sub-iter: read tile kt+2 frags; stage kt+4; MFMA tile kt+1
    if (kt + 2 < NT) { READ_FRAGS(a0A, a1A, bA, (kt + 2) & 3); }
    STAGE(kt + 4);
    MFMA_CLUSTER(a0B, a1B, bB);
    if (kt + 2 < NT) { BOUNDARY(kt + 1); }
  }

  // ---- epilogue: y = acc * scale[col] + bias[col]
  const int crow = (lane >> 4) * 4;  // C/D: row=(lane>>4)*4+reg, col=lane&15 (m89)
  const int ccol = lane & 15;
  #pragma unroll
  for (int n = 0; n < 4; ++n) {
    const int col  = bn0 + wcn * 64 + n * 16 + ccol;
    const float sc = scale[col];
    const float bz = bias[col];
    #pragma unroll
    for (int m = 0; m < 8; ++m) {
      const int row0 = bm0 + wr * 128 + m * 16 + crow;
      float* yp = Y + (size_t)row0 * NTOT + col;
      #pragma unroll
      for (int r = 0; r < 4; ++r)
        yp[(size_t)r * NTOT] = acc[m][n][r] * sc + bz;
    }
  }
}

// ---------------- fallback: fused kernel (round-2 passing version) ----------------

static constexpr int FBM = 128, FBN = 128, FBK = 64;
static constexpr int LDSS = 72;
static constexpr int FNSTEP = KTOT / FBK;

__global__ __launch_bounds__(256) void int4_linear_fused_kernel(
    const float* __restrict__ X,
    const uint32_t* __restrict__ Wp,
    const float* __restrict__ scale,
    const float* __restrict__ bias,
    float* __restrict__ Y)
{
  __shared__ ushort As[FBM * LDSS];
  __shared__ ushort Bs[FBN * LDSS];

  const int t    = threadIdx.x;
  const int lane = t & 63;
  const int wv   = t >> 6;
  const int wr   = wv >> 1;
  const int wc   = wv & 1;
  const int bm0 = blockIdx.y * FBM;
  const int bn0 = blockIdx.x * FBN;
  const int srow = t >> 1;
  const int sh   = t & 1;

  const float*    ag = X  + (size_t)(bm0 + srow) * KTOT + sh * 32;
  const uint32_t* bg = Wp + (size_t)(bn0 + srow) * (KTOT / 2) + sh * 16;

  float4 areg[8];
  uint4  breg[4];
  #pragma unroll
  for (int j = 0; j < 8; ++j) areg[j] = *reinterpret_cast<const float4*>(ag + j * 4);
  #pragma unroll
  for (int j = 0; j < 4; ++j) breg[j] = *reinterpret_cast<const uint4*>(bg + j * 4);

  floatx4 acc[4][4];
  #pragma unroll
  for (int m = 0; m < 4; ++m)
    #pragma unroll
    for (int n = 0; n < 4; ++n)
      acc[m][n] = (floatx4){0.f, 0.f, 0.f, 0.f};

  ushort* adst = &As[srow * LDSS + sh * 32];
  ushort* bdst = &Bs[srow * LDSS + sh * 32];

  for (int ks = 0; ks < FNSTEP; ++ks) {
    {
      uint32_t ab[16];
      #pragma unroll
      for (int j = 0; j < 8; ++j) {
        uint32_t u0 = __builtin_bit_cast(uint32_t, areg[j].x) + 0x8000u;
        uint32_t u1 = __builtin_bit_cast(uint32_t, areg[j].y) + 0x8000u;
        uint32_t u2 = __builtin_bit_cast(uint32_t, areg[j].z) + 0x8000u;
        uint32_t u3 = __builtin_bit_cast(uint32_t, areg[j].w) + 0x8000u;
        ab[2*j]   = __builtin_amdgcn_perm(u1, u0, 0x07060302u);
        ab[2*j+1] = __builtin_amdgcn_perm(u3, u2, 0x07060302u);
      }
      uint32_t bb[16];
      #pragma unroll
      for (int j = 0; j < 4; ++j) {
        const uint32_t wq[4] = {breg[j].x, breg[j].y, breg[j].z, breg[j].w};
        #pragma unroll
        for (int p2 = 0; p2 < 4; ++p2) {
          const uint32_t w = wq[p2];
          int v0 = ((int)(w << 28)) >> 28;
          int v1 = ((int)(w << 24)) >> 28;
          uint32_t f0 = __builtin_bit_cast(uint32_t, (float)v0);
          uint32_t f1 = __builtin_bit_cast(uint32_t, (float)v1);
          bb[j*4 + p2] = __builtin_amdgcn_perm(f1, f0, 0x07060302u);
        }
      }
      #pragma unroll
      for (int j = 0; j < 4; ++j) {
        *reinterpret_cast<uint4*>(adst + j * 8) = *reinterpret_cast<const uint4*>(&ab[j*4]);
        *reinterpret_cast<uint4*>(bdst + j * 8) = *reinterpret_cast<const uint4*>(&bb[j*4]);
      }
    }
    __syncthreads();

    if (ks + 1 < FNSTEP) {
      const float*    ap = ag + (ks + 1) * FBK;
      const uint32_t* bp = bg + (ks + 1) * (FBK / 2);
      #pragma unroll
      for (int j = 0; j < 8; ++j) areg[j] = *reinterpret_cast<const float4*>(ap + j * 4);
      #pragma unroll
      for (int j = 0; j < 4; ++j) breg[j] = *reinterpret_cast<const uint4*>(bp + j * 4);
    }

    #pragma unroll
    for (int kk = 0; kk < 2; ++kk) {
      const int ko = kk * 32 + (lane >> 4) * 8;
      short8 af[4], bf[4];
      #pragma unroll
      for (int m = 0; m < 4; ++m)
        af[m] = *reinterpret_cast<const short8*>(&As[(wr*64 + m*16 + (lane & 15)) * LDSS + ko]);
      #pragma unroll
      for (int n = 0; n < 4; ++n)
        bf[n] = *reinterpret_cast<const short8*>(&Bs[(wc*64 + n*16 + (lane & 15)) * LDSS + ko]);
      #pragma unroll
      for (int m = 0; m < 4; ++m)
        #pragma unroll
        for (int n = 0; n < 4; ++n)
          acc[m][n] = __builtin_amdgcn_mfma_f32_16x16x32_bf16(af[m], bf[n], acc[m][n], 0, 0, 0);
    }
    __syncthreads();
  }

  const int crow = (lane >> 4) * 4;
  const int ccol = lane & 15;
  #pragma unroll
  for (int n = 0; n < 4; ++n) {
    const int col  = bn0 + wc * 64 + n * 16 + ccol;
    const float sv = scale[col];
    const float bz = bias[col];
    #pragma unroll
    for (int m = 0; m < 4; ++m) {
      const int row0 = bm0 + wr * 64 + m * 16 + crow;
      float* yp = Y + (size_t)row0 * NTOT + col;
      #pragma unroll
      for (int r = 0; r < 4; ++r)
        yp[(size_t)r * NTOT] = acc[m][n][r] * sv + bz;
    }
  }
}

// ---------------- launch ----------------

extern "C" void kernel_launch(void* const* d_in, const int* in_sizes, int n_in,
                              void* d_out, int out_size, void* d_ws, size_t ws_size,
                              hipStream_t stream) {
  (void)in_sizes; (void)n_in; (void)out_size;
  const float*    X     = (const float*)d_in[0];
  const uint32_t* Wp    = (const uint32_t*)d_in[1];
  const float*    scale = (const float*)d_in[2];
  const float*    bias  = (const float*)d_in[3];
  float*          Y     = (float*)d_out;

  const size_t xb_bytes = (size_t)MTOT * KTOT * 2;          // 67 MB
  const size_t wb_bytes = (size_t)NTOT * KTOT * 2;          // 134 MB
  if (ws_size >= xb_bytes + wb_bytes) {
    ushort* Xb = (ushort*)d_ws;
    ushort* Wb = (ushort*)((char*)d_ws + xb_bytes);
    cvt_x_kernel<<<(MTOT * KTOT) / (8 * 256), 256, 0, stream>>>(X, Xb);
    cvt_w_kernel<<<(NTOT * KTOT / 2) / (4 * 256), 256, 0, stream>>>(Wp, Wb);
    gemm_bf16_256_kernel<<<(MTOT / BM) * (NTOT / BN), 512, 0, stream>>>(Xb, Wb, scale, bias, Y);
  } else {
    dim3 grid(NTOT / FBN, MTOT / FBM);
    int4_linear_fused_kernel<<<grid, 256, 0, stream>>>(X, Wp, scale, bias, Y);
  }
}